// Round 11
// baseline (253.128 us; speedup 1.0000x reference)
//
#include <hip/hip_runtime.h>
#include <hip/hip_bf16.h>
#include <stdint.h>

#define M_DIM 2048
#define N_DIM 4096
#define K_DIM 4096

#define BM 128
#define BN 128
#define BK 64

typedef __attribute__((ext_vector_type(8))) short short8;
typedef __attribute__((ext_vector_type(4))) float f32x4;

// d_in[1]: fp8 weight UPLOADED AS FLOAT32 by the harness (confirmed r9: PASS).
// Values are exact e4m3 reals; bf16 conversion is lossless (4-bit significand).
//
// Fully fused: C[M][N] = (x*s -> bf16) @ (w -> bf16)^T, one kernel, no d_ws.
//   - scale s[n/128][k/128] is wave-uniform per (WG, k-tile) since BN==128 and
//     BK==64 divides 128: fold into A staging ((x*s)*w == x*(w*s)).
//   - both tiles reg-staged (global f32x4 loads + cvt + ds_write_b128); this
//     staging structure is determinism-validated (r1==r3) and the MFMA core +
//     C/D epilogue passed in r9 (absmax 2.0).
// 128x128 tile, BK=64, 4 waves (2x2), mfma_f32_16x16x32_bf16, 4x4 frags/wave.
__global__ __launch_bounds__(256) void gemm_fused(const float* __restrict__ X,
                                                  const float* __restrict__ Wf,
                                                  const float* __restrict__ S,
                                                  float* __restrict__ C) {
    __shared__ __hip_bfloat16 As[BM * BK] __attribute__((aligned(16)));
    __shared__ __hip_bfloat16 Bs[BN * BK] __attribute__((aligned(16)));

    const int tid  = threadIdx.x;
    const int wave = tid >> 6;
    const int lane = tid & 63;

    // XCD-aware bijective swizzle (nwg = 512, divisible by 8)
    const int nwg = (M_DIM / BM) * (N_DIM / BN);
    const int wg  = ((int)blockIdx.x & 7) * (nwg >> 3) + ((int)blockIdx.x >> 3);
    const int br  = wg & (M_DIM / BM - 1);    // 0..15
    const int bc  = wg / (M_DIM / BM);        // 0..31

    const int wm = wave >> 1;  // 0..1
    const int wn = wave & 1;   // 0..1

    f32x4 acc[4][4];
#pragma unroll
    for (int i = 0; i < 4; ++i)
#pragma unroll
        for (int j = 0; j < 4; ++j) acc[i][j] = (f32x4)0.0f;

    const int lrow = lane & 15;
    const int lk   = (lane >> 4) << 3;   // 0,8,16,24

    for (int kt = 0; kt < K_DIM / BK; ++kt) {
        // wave-uniform block scale (BN==128 -> one n-block; BK=64 -> k-block kt>>1)
        const float sc = S[bc * (K_DIM / 128) + (kt >> 1)];

        // ---- A: 128x64 f32 -> (x*sc) -> bf16, 4 passes x 8 elems/thread ----
#pragma unroll
        for (int p = 0; p < 4; ++p) {
            int e = p * 2048 + tid * 8, r = e >> 6, k0 = e & 63;
            const float* gp = X + (size_t)(br * BM + r) * K_DIM + (size_t)kt * BK + k0;
            float4 f0 = *reinterpret_cast<const float4*>(gp);
            float4 f1 = *reinterpret_cast<const float4*>(gp + 4);
            __hip_bfloat16 t[8] __attribute__((aligned(16)));
            t[0] = __float2bfloat16(f0.x * sc); t[1] = __float2bfloat16(f0.y * sc);
            t[2] = __float2bfloat16(f0.z * sc); t[3] = __float2bfloat16(f0.w * sc);
            t[4] = __float2bfloat16(f1.x * sc); t[5] = __float2bfloat16(f1.y * sc);
            t[6] = __float2bfloat16(f1.z * sc); t[7] = __float2bfloat16(f1.w * sc);
            *reinterpret_cast<uint4*>(&As[e]) = *reinterpret_cast<const uint4*>(t);
        }
        // ---- B: 128x64 f32 -> bf16 (lossless for e4m3 values) ----
#pragma unroll
        for (int p = 0; p < 4; ++p) {
            int e = p * 2048 + tid * 8, r = e >> 6, k0 = e & 63;
            const float* gp = Wf + (size_t)(bc * BN + r) * K_DIM + (size_t)kt * BK + k0;
            float4 f0 = *reinterpret_cast<const float4*>(gp);
            float4 f1 = *reinterpret_cast<const float4*>(gp + 4);
            __hip_bfloat16 t[8] __attribute__((aligned(16)));
            t[0] = __float2bfloat16(f0.x); t[1] = __float2bfloat16(f0.y);
            t[2] = __float2bfloat16(f0.z); t[3] = __float2bfloat16(f0.w);
            t[4] = __float2bfloat16(f1.x); t[5] = __float2bfloat16(f1.y);
            t[6] = __float2bfloat16(f1.z); t[7] = __float2bfloat16(f1.w);
            *reinterpret_cast<uint4*>(&Bs[e]) = *reinterpret_cast<const uint4*>(t);
        }
        __syncthreads();

        // ---- compute: 2 K-subtiles of 32, 16 MFMA each ----
#pragma unroll
        for (int kk = 0; kk < 2; ++kk) {
            short8 a[4], b[4];
#pragma unroll
            for (int i = 0; i < 4; ++i)
                a[i] = *reinterpret_cast<const short8*>(&As[(wm * 64 + i * 16 + lrow) * BK + kk * 32 + lk]);
#pragma unroll
            for (int j = 0; j < 4; ++j)
                b[j] = *reinterpret_cast<const short8*>(&Bs[(wn * 64 + j * 16 + lrow) * BK + kk * 32 + lk]);
#pragma unroll
            for (int i = 0; i < 4; ++i)
#pragma unroll
                for (int j = 0; j < 4; ++j)
                    acc[i][j] = __builtin_amdgcn_mfma_f32_16x16x32_bf16(a[i], b[j], acc[i][j], 0, 0, 0);
        }
        __syncthreads();
    }

    // ---- epilogue: C/D layout col=lane&15, row=(lane>>4)*4+reg (r9-verified) ----
    const int crow0 = br * BM + wm * 64 + ((lane >> 4) << 2);
    const int ccol0 = bc * BN + wn * 64 + (lane & 15);
#pragma unroll
    for (int i = 0; i < 4; ++i)
#pragma unroll
        for (int j = 0; j < 4; ++j)
#pragma unroll
            for (int v = 0; v < 4; ++v)
                C[(size_t)(crow0 + i * 16 + v) * N_DIM + ccol0 + j * 16] = acc[i][j][v];
}

extern "C" void kernel_launch(void* const* d_in, const int* in_sizes, int n_in,
                              void* d_out, int out_size, void* d_ws, size_t ws_size,
                              hipStream_t stream) {
    (void)in_sizes; (void)n_in; (void)out_size; (void)d_ws; (void)ws_size;
    const float* x  = (const float*)d_in[0];
    const float* w  = (const float*)d_in[1];   // fp8 values upcast to f32 (confirmed r9)
    const float* s  = (const float*)d_in[2];
    float* out      = (float*)d_out;

    gemm_fused<<<(M_DIM / BM) * (N_DIM / BN), 256, 0, stream>>>(x, w, s, out);
}

// Round 14
// 226.041 us; speedup vs baseline: 1.1198x; 1.1198x over previous
//
#include <hip/hip_runtime.h>
#include <hip/hip_bf16.h>
#include <stdint.h>

#define M_DIM 2048
#define N_DIM 4096
#define K_DIM 4096

#define BM 128
#define BN 128
#define BK 64

typedef __attribute__((ext_vector_type(8))) short short8;
typedef __attribute__((ext_vector_type(4))) float f32x4;

typedef __attribute__((address_space(3))) char lds_byte;
typedef const __attribute__((address_space(1))) char gbl_byte;

// d_in[1]: fp8 weight uploaded as FLOAT32 (confirmed r9). Values are exact e4m3
// reals; bf16 conversion lossless. Split structure (kernel_sum model, r11):
// prepass ~23us + GEMM. GEMM upgraded 4-wave -> 8-wave WGs: grid 512 x 512thr
// = 16 waves/CU (was 8) to attack the latency-bound profile (r9: occ 20.7%,
// MfmaUtil 25.5%).

// ---------------- x: f32 -> bf16 (8 elems/thread) --------------------------------
__global__ __launch_bounds__(256) void convert_x(const float* __restrict__ x,
                                                 __hip_bfloat16* __restrict__ o) {
    size_t i = ((size_t)blockIdx.x * 256 + threadIdx.x) * 8;
    float4 a = *reinterpret_cast<const float4*>(x + i);
    float4 b = *reinterpret_cast<const float4*>(x + i + 4);
    __hip_bfloat16 t[8] __attribute__((aligned(16)));
    t[0] = __float2bfloat16(a.x); t[1] = __float2bfloat16(a.y);
    t[2] = __float2bfloat16(a.z); t[3] = __float2bfloat16(a.w);
    t[4] = __float2bfloat16(b.x); t[5] = __float2bfloat16(b.y);
    t[6] = __float2bfloat16(b.z); t[7] = __float2bfloat16(b.w);
    *reinterpret_cast<uint4*>(o + i) = *reinterpret_cast<const uint4*>(t);
}

// ---------------- W: f32 * blockscale -> bf16 (8 elems/thread) -------------------
__global__ __launch_bounds__(256) void dequant_w(const float* __restrict__ w,
                                                 const float* __restrict__ s,
                                                 __hip_bfloat16* __restrict__ o) {
    int idx = blockIdx.x * 256 + threadIdx.x;
    int n   = idx >> 9;
    int k0  = (idx & 511) << 3;
    float sc = s[(n >> 7) * (K_DIM / 128) + (k0 >> 7)];
    const float* gp = w + (size_t)n * K_DIM + k0;
    float4 a = *reinterpret_cast<const float4*>(gp);
    float4 b = *reinterpret_cast<const float4*>(gp + 4);
    __hip_bfloat16 t[8] __attribute__((aligned(16)));
    t[0] = __float2bfloat16(a.x * sc); t[1] = __float2bfloat16(a.y * sc);
    t[2] = __float2bfloat16(a.z * sc); t[3] = __float2bfloat16(a.w * sc);
    t[4] = __float2bfloat16(b.x * sc); t[5] = __float2bfloat16(b.y * sc);
    t[6] = __float2bfloat16(b.z * sc); t[7] = __float2bfloat16(b.w * sc);
    *reinterpret_cast<uint4*>(o + (size_t)n * K_DIM + k0) = *reinterpret_cast<const uint4*>(t);
}

// ---------------- bf16 B^T GEMM, 8 waves (2M x 4N), r9-verified mechanics --------
__global__ __launch_bounds__(512) void gemm_bt8(const __hip_bfloat16* __restrict__ A,
                                                const __hip_bfloat16* __restrict__ B,
                                                float* __restrict__ C) {
    __shared__ __hip_bfloat16 As[BM * BK] __attribute__((aligned(16)));
    __shared__ __hip_bfloat16 Bs[BN * BK] __attribute__((aligned(16)));

    const int tid  = threadIdx.x;
    const int wave = tid >> 6;     // 0..7
    const int lane = tid & 63;

    const int nwg = (M_DIM / BM) * (N_DIM / BN);   // 512, %8==0
    const int wg  = ((int)blockIdx.x & 7) * (nwg >> 3) + ((int)blockIdx.x >> 3);
    const int br  = wg & (M_DIM / BM - 1);
    const int bc  = wg / (M_DIM / BM);

    const size_t a_base = (size_t)br * BM * K_DIM;
    const size_t b_base = (size_t)bc * BN * K_DIM;

    const int wm = wave >> 2;      // 0..1 -> M half (64 rows)
    const int wn = wave & 3;       // 0..3 -> N quarter (32 cols)

    f32x4 acc[4][2];
#pragma unroll
    for (int i = 0; i < 4; ++i)
#pragma unroll
        for (int j = 0; j < 2; ++j) acc[i][j] = (f32x4)0.0f;

    const int lrow = lane & 15;
    const int lk   = (lane >> 4) << 3;   // 0,8,16,24

    for (int kt = 0; kt < K_DIM / BK; ++kt) {
        // stage A,B: 16 chunks of 1KB each matrix; 8 waves x 2 chunks
#pragma unroll
        for (int c = 0; c < 2; ++c) {
            int chunk = wave * 2 + c;                 // 0..15
            int bo    = chunk * 1024 + lane * 16;
            int row   = bo >> 7;                      // 128 B per row
            int colb  = bo & 127;
            const char* ga = (const char*)A + (a_base + (size_t)row * K_DIM) * 2 + kt * (BK * 2) + colb;
            const char* gb = (const char*)B + (b_base + (size_t)row * K_DIM) * 2 + kt * (BK * 2) + colb;
            __builtin_amdgcn_global_load_lds((gbl_byte*)ga, (lds_byte*)((char*)As + chunk * 1024), 16, 0, 0);
            __builtin_amdgcn_global_load_lds((gbl_byte*)gb, (lds_byte*)((char*)Bs + chunk * 1024), 16, 0, 0);
        }
        __syncthreads();

#pragma unroll
        for (int kk = 0; kk < 2; ++kk) {
            short8 a[4], b[2];
#pragma unroll
            for (int i = 0; i < 4; ++i)
                a[i] = *reinterpret_cast<const short8*>(&As[(wm * 64 + i * 16 + lrow) * BK + kk * 32 + lk]);
#pragma unroll
            for (int j = 0; j < 2; ++j)
                b[j] = *reinterpret_cast<const short8*>(&Bs[(wn * 32 + j * 16 + lrow) * BK + kk * 32 + lk]);
#pragma unroll
            for (int i = 0; i < 4; ++i)
#pragma unroll
                for (int j = 0; j < 2; ++j)
                    acc[i][j] = __builtin_amdgcn_mfma_f32_16x16x32_bf16(a[i], b[j], acc[i][j], 0, 0, 0);
        }
        __syncthreads();
    }

    // epilogue: C/D layout col=lane&15, row=(lane>>4)*4+reg (r9-verified)
    const int crow0 = br * BM + wm * 64 + ((lane >> 4) << 2);
    const int ccol0 = bc * BN + wn * 32 + (lane & 15);
#pragma unroll
    for (int i = 0; i < 4; ++i)
#pragma unroll
        for (int j = 0; j < 2; ++j)
#pragma unroll
            for (int v = 0; v < 4; ++v)
                C[(size_t)(crow0 + i * 16 + v) * N_DIM + ccol0 + j * 16] = acc[i][j][v];
}

// ---------------- fused fallback (ws too small) — r11-verified PASS --------------
__global__ __launch_bounds__(256) void gemm_fused(const float* __restrict__ X,
                                                  const float* __restrict__ Wf,
                                                  const float* __restrict__ S,
                                                  float* __restrict__ C) {
    __shared__ __hip_bfloat16 As[BM * BK] __attribute__((aligned(16)));
    __shared__ __hip_bfloat16 Bs[BN * BK] __attribute__((aligned(16)));

    const int tid  = threadIdx.x;
    const int wave = tid >> 6;
    const int lane = tid & 63;

    const int nwg = (M_DIM / BM) * (N_DIM / BN);
    const int wg  = ((int)blockIdx.x & 7) * (nwg >> 3) + ((int)blockIdx.x >> 3);
    const int br  = wg & (M_DIM / BM - 1);
    const int bc  = wg / (M_DIM / BM);

    const int wm = wave >> 1;
    const int wn = wave & 1;

    f32x4 acc[4][4];
#pragma unroll
    for (int i = 0; i < 4; ++i)
#pragma unroll
        for (int j = 0; j < 4; ++j) acc[i][j] = (f32x4)0.0f;

    const int lrow = lane & 15;
    const int lk   = (lane >> 4) << 3;

    for (int kt = 0; kt < K_DIM / BK; ++kt) {
        const float sc = S[bc * (K_DIM / 128) + (kt >> 1)];
#pragma unroll
        for (int p = 0; p < 4; ++p) {
            int e = p * 2048 + tid * 8, r = e >> 6, k0 = e & 63;
            const float* gp = X + (size_t)(br * BM + r) * K_DIM + (size_t)kt * BK + k0;
            float4 f0 = *reinterpret_cast<const float4*>(gp);
            float4 f1 = *reinterpret_cast<const float4*>(gp + 4);
            __hip_bfloat16 t[8] __attribute__((aligned(16)));
            t[0] = __float2bfloat16(f0.x * sc); t[1] = __float2bfloat16(f0.y * sc);
            t[2] = __float2bfloat16(f0.z * sc); t[3] = __float2bfloat16(f0.w * sc);
            t[4] = __float2bfloat16(f1.x * sc); t[5] = __float2bfloat16(f1.y * sc);
            t[6] = __float2bfloat16(f1.z * sc); t[7] = __float2bfloat16(f1.w * sc);
            *reinterpret_cast<uint4*>(&As[e]) = *reinterpret_cast<const uint4*>(t);
        }
#pragma unroll
        for (int p = 0; p < 4; ++p) {
            int e = p * 2048 + tid * 8, r = e >> 6, k0 = e & 63;
            const float* gp = Wf + (size_t)(bc * BN + r) * K_DIM + (size_t)kt * BK + k0;
            float4 f0 = *reinterpret_cast<const float4*>(gp);
            float4 f1 = *reinterpret_cast<const float4*>(gp + 4);
            __hip_bfloat16 t[8] __attribute__((aligned(16)));
            t[0] = __float2bfloat16(f0.x); t[1] = __float2bfloat16(f0.y);
            t[2] = __float2bfloat16(f0.z); t[3] = __float2bfloat16(f0.w);
            t[4] = __float2bfloat16(f1.x); t[5] = __float2bfloat16(f1.y);
            t[6] = __float2bfloat16(f1.z); t[7] = __float2bfloat16(f1.w);
            *reinterpret_cast<uint4*>(&Bs[e]) = *reinterpret_cast<const uint4*>(t);
        }
        __syncthreads();
#pragma unroll
        for (int kk = 0; kk < 2; ++kk) {
            short8 a[4], b[4];
#pragma unroll
            for (int i = 0; i < 4; ++i)
                a[i] = *reinterpret_cast<const short8*>(&As[(wm * 64 + i * 16 + lrow) * BK + kk * 32 + lk]);
#pragma unroll
            for (int j = 0; j < 4; ++j)
                b[j] = *reinterpret_cast<const short8*>(&Bs[(wn * 64 + j * 16 + lrow) * BK + kk * 32 + lk]);
#pragma unroll
            for (int i = 0; i < 4; ++i)
#pragma unroll
                for (int j = 0; j < 4; ++j)
                    acc[i][j] = __builtin_amdgcn_mfma_f32_16x16x32_bf16(a[i], b[j], acc[i][j], 0, 0, 0);
        }
        __syncthreads();
    }

    const int crow0 = br * BM + wm * 64 + ((lane >> 4) << 2);
    const int ccol0 = bc * BN + wn * 64 + (lane & 15);
#pragma unroll
    for (int i = 0; i < 4; ++i)
#pragma unroll
        for (int j = 0; j < 4; ++j)
#pragma unroll
            for (int v = 0; v < 4; ++v)
                C[(size_t)(crow0 + i * 16 + v) * N_DIM + ccol0 + j * 16] = acc[i][j][v];
}

extern "C" void kernel_launch(void* const* d_in, const int* in_sizes, int n_in,
                              void* d_out, int out_size, void* d_ws, size_t ws_size,
                              hipStream_t stream) {
    (void)in_sizes; (void)n_in; (void)out_size;
    const float* x  = (const float*)d_in[0];
    const float* w  = (const float*)d_in[1];
    const float* s  = (const float*)d_in[2];
    float* out      = (float*)d_out;

    const size_t xb_bytes = (size_t)M_DIM * K_DIM * 2;
    const size_t wb_bytes = (size_t)N_DIM * K_DIM * 2;
    if (ws_size >= xb_bytes + wb_bytes) {
        __hip_bfloat16* xb = (__hip_bfloat16*)d_ws;
        __hip_bfloat16* wb = (__hip_bfloat16*)((char*)d_ws + xb_bytes);
        convert_x<<<(M_DIM * K_DIM / 8) / 256, 256, 0, stream>>>(x, xb);
        dequant_w<<<(N_DIM * K_DIM / 8) / 256, 256, 0, stream>>>(w, s, wb);
        gemm_bt8<<<(M_DIM / BM) * (N_DIM / BN), 512, 0, stream>>>(xb, wb, out);
    } else {
        gemm_fused<<<(M_DIM / BM) * (N_DIM / BN), 256, 0, stream>>>(x, w, s, out);
    }
}